// Round 5
// baseline (13635.077 us; speedup 1.0000x reference)
//
#include <hip/hip_runtime.h>
#include <cstdint>
#include <cstddef>

#define HDIM 2048
#define NCLS 11
#define NBLK 256
#define NTHR 256
#define EPB  (HDIM / NBLK)      // 8 h-elements per block
#define CHUNK 256               // h-columns per lane (weights in VGPR/AGPR)
#define CPAD  260               // padded chunk stride in LDS floats
#define MAXS 8192               // max supported steps (counter array bound)

// d_ws layout:
//   [0, cnt_bytes)        done[t] counters, one per step, PADU uints apart
//   [hoff, +8KB)          hbuf0 (h for even t)
//   [hoff+8KB, +8KB)      hbuf1 (h for odd t)
// done[] is memset to 0 each launch; counters are never reused across steps.

__device__ __forceinline__ float waveReduceSum(float v) {
#pragma unroll
    for (int off = 32; off > 0; off >>= 1) v += __shfl_xor(v, off, 64);
    return v;
}

// Weight-stationary persistent LSTM with single-line step counters.
// Block b owns h[b*8..b*8+8); wave w = gate w; lane (rl=lane>>3, cc=lane&7)
// owns row w*2048+b*8+rl, columns [cc*256, cc*256+256) held in registers.
__global__ void __launch_bounds__(NTHR, 1) lstm_persistent(
    const float* __restrict__ x0,
    const float* __restrict__ Wih,
    const float* __restrict__ Whh,
    const float* __restrict__ bih,
    const float* __restrict__ bhh,
    const float* __restrict__ Wout,
    const float* __restrict__ bout,
    const int* __restrict__ stepsp,
    float* __restrict__ out,
    float* __restrict__ hbuf0,
    float* __restrict__ hbuf1,
    unsigned* __restrict__ done,
    int padu)
{
    const int tid  = threadIdx.x;
    const int wave = tid >> 6;          // gate (i,f,g,o)
    const int lane = tid & 63;
    const int rl   = lane >> 3;         // row within gate for this block
    const int cc   = lane & 7;          // column chunk
    const int bid  = blockIdx.x;
    const int jb   = bid * EPB;

    __shared__ float hlds[8 * CPAD];
    __shared__ float gsm[4 * EPB];
    __shared__ float csm[EPB];

    const int row = wave * HDIM + jb + rl;
    const size_t sbase = (size_t)row * HDIM + (size_t)cc * CHUNK;

    // prefill: w = W_ih slice (step 0 uses W_ih alone since h0 = 0)
    float w[CHUNK];
#pragma unroll
    for (int jj = 0; jj < 64; ++jj) {
        float4 v = *(const float4*)(Wih + sbase + (size_t)jj * 4);
        w[4 * jj + 0] = v.x; w[4 * jj + 1] = v.y;
        w[4 * jj + 2] = v.z; w[4 * jj + 3] = v.w;
    }
    const float bsum = bih[row] + bhh[row];
    if (tid < EPB) csm[tid] = 0.0f;

    int steps = stepsp[0];
    if (steps > MAXS) steps = MAXS;
    const int e0   = tid * 8;                              // h elems this thread stages
    const int soff = (tid >> 5) * CPAD + (tid & 31) * 8;   // LDS address of e0

    for (int t = 0; t < steps; ++t) {
        if (t == 0) {
#pragma unroll
            for (int i = 0; i < 8; ++i) hlds[soff + i] = x0[e0 + i];
        } else {
            const float* hb = (t & 1) ? hbuf1 : hbuf0;
            if (tid == 0) {
                unsigned* cnt = done + (size_t)t * padu;
                while (__hip_atomic_load(cnt, __ATOMIC_RELAXED,
                                         __HIP_MEMORY_SCOPE_AGENT) < (unsigned)NBLK)
                    __builtin_amdgcn_s_sleep(2);
            }
            __syncthreads();
            __threadfence();            // acquire: invalidate stale cached lines
#pragma unroll
            for (int i = 0; i < 8; ++i)
                hlds[soff + i] = __hip_atomic_load(hb + e0 + i, __ATOMIC_RELAXED,
                                                   __HIP_MEMORY_SCOPE_AGENT);
        }
        __syncthreads();

        // dot: 256 register weights x LDS-broadcast h chunk
        const float* hc = &hlds[cc * CPAD];
        float ax = 0.f, ay = 0.f, az = 0.f, aw = 0.f;
#pragma unroll
        for (int jj = 0; jj < 64; ++jj) {
            float4 hv = *(const float4*)(hc + jj * 4);
            ax += w[4 * jj + 0] * hv.x;
            ay += w[4 * jj + 1] * hv.y;
            az += w[4 * jj + 2] * hv.z;
            aw += w[4 * jj + 3] * hv.w;
        }
        float part = (ax + ay) + (az + aw);
        part += __shfl_xor(part, 1, 64);
        part += __shfl_xor(part, 2, 64);
        part += __shfl_xor(part, 4, 64);        // summed over cc
        if (cc == 0) gsm[wave * EPB + rl] = part + bsum;
        __syncthreads();

        float* wb = ((t + 1) & 1) ? hbuf1 : hbuf0;
        if (tid < EPB) {
            float gi = gsm[0 * EPB + tid];
            float gf = gsm[1 * EPB + tid];
            float gg = gsm[2 * EPB + tid];
            float go = gsm[3 * EPB + tid];
            float si = 1.0f / (1.0f + expf(-gi));
            float sf = 1.0f / (1.0f + expf(-gf));
            float tg = tanhf(gg);
            float so = 1.0f / (1.0f + expf(-go));
            float c  = sf * csm[tid] + si * tg;
            csm[tid] = c;
            __hip_atomic_store(wb + jb + tid, so * tanhf(c),
                               __ATOMIC_RELAXED, __HIP_MEMORY_SCOPE_AGENT);
        }
        __syncthreads();                        // h stores drained before release
        if (tid == 0) {
            __threadfence();                    // release: h visible device-wide
            atomicAdd(done + (size_t)(t + 1) * padu, 1u);
        }

        if (t == 0) {
            // switch weights to Wc = W_ih + W_hh for steps >= 1
#pragma unroll
            for (int jj = 0; jj < 64; ++jj) {
                float4 v = *(const float4*)(Whh + sbase + (size_t)jj * 4);
                w[4 * jj + 0] += v.x; w[4 * jj + 1] += v.y;
                w[4 * jj + 2] += v.z; w[4 * jj + 3] += v.w;
            }
        }
    }

    // final c
    if (tid < EPB) out[NCLS + HDIM + jb + tid] = csm[tid];

    // block 0: wait for h_steps, classifier head + h copy
    if (bid == 0) {
        const float* hb = (steps & 1) ? hbuf1 : hbuf0;
        if (tid == 0) {
            unsigned* cnt = done + (size_t)steps * padu;
            while (__hip_atomic_load(cnt, __ATOMIC_RELAXED,
                                     __HIP_MEMORY_SCOPE_AGENT) < (unsigned)NBLK)
                __builtin_amdgcn_s_sleep(2);
        }
        __syncthreads();
        __threadfence();
#pragma unroll
        for (int i = 0; i < 8; ++i)
            hlds[soff + i] = __hip_atomic_load(hb + e0 + i, __ATOMIC_RELAXED,
                                               __HIP_MEMORY_SCOPE_AGENT);
        __syncthreads();

        __shared__ float lsm[NCLS];
        float hr[8][4];
#pragma unroll
        for (int k = 0; k < 8; ++k)
#pragma unroll
            for (int c = 0; c < 4; ++c)
                hr[k][c] = hlds[k * CPAD + lane * 4 + c];
        for (int r = wave; r < NCLS; r += 4) {
            const float4* w4 = (const float4*)(Wout + (size_t)r * HDIM);
            float sx = 0.f, sy = 0.f, sz = 0.f, sw4 = 0.f;
#pragma unroll
            for (int k = 0; k < 8; ++k) {
                float4 wv = w4[k * 64 + lane];
                sx  += wv.x * hr[k][0];
                sy  += wv.y * hr[k][1];
                sz  += wv.z * hr[k][2];
                sw4 += wv.w * hr[k][3];
            }
            float s = waveReduceSum((sx + sy) + (sz + sw4));
            if (lane == 0) lsm[r] = s + bout[r];
        }
        __syncthreads();
        if (tid == 0) {
            float m = lsm[0];
            for (int r = 1; r < NCLS; ++r) m = fmaxf(m, lsm[r]);
            float ex[NCLS];
            float den = 0.0f;
            for (int r = 0; r < NCLS; ++r) { ex[r] = expf(lsm[r] - m); den += ex[r]; }
            float inv = 1.0f / den;
            for (int r = 0; r < NCLS; ++r) out[r] = ex[r] * inv;
        }
#pragma unroll
        for (int i = 0; i < 8; ++i)
            out[NCLS + e0 + i] = hlds[soff + i];
    }
}

extern "C" void kernel_launch(void* const* d_in, const int* in_sizes, int n_in,
                              void* d_out, int out_size, void* d_ws, size_t ws_size,
                              hipStream_t stream) {
    const float* x0    = (const float*)d_in[0];   // row 0 of inputs
    const float* Wih   = (const float*)d_in[1];
    const float* Whh   = (const float*)d_in[2];
    const float* bih   = (const float*)d_in[3];
    const float* bhh   = (const float*)d_in[4];
    const float* Wout  = (const float*)d_in[5];
    const float* bout  = (const float*)d_in[6];
    const int*   steps = (const int*)d_in[7];
    float* out = (float*)d_out;

    // counter padding: 16 uints (64 B line) if workspace allows, else packed
    int padu = 16;
    size_t cnt_bytes = (size_t)(MAXS + 1) * padu * sizeof(unsigned);   // ~524 KB
    size_t hbytes = (size_t)HDIM * sizeof(float);                      // 8 KB
    if (ws_size < cnt_bytes + 2 * hbytes + 1024) {
        padu = 1;
        cnt_bytes = (size_t)(MAXS + 1) * sizeof(unsigned);             // ~32 KB
    }
    size_t hoff = (cnt_bytes + 511) & ~(size_t)511;

    float* hbuf0 = (float*)((char*)d_ws + hoff);
    float* hbuf1 = hbuf0 + HDIM;
    unsigned* done = (unsigned*)d_ws;

    // zero the step counters each launch (graph-capture safe, deterministic)
    hipMemsetAsync(d_ws, 0, cnt_bytes, stream);

    lstm_persistent<<<dim3(NBLK), dim3(NTHR), 0, stream>>>(
        x0, Wih, Whh, bih, bhh, Wout, bout, steps, out,
        hbuf0, hbuf1, done, padu);
}

// Round 6
// 2997.020 us; speedup vs baseline: 4.5495x; 4.5495x over previous
//
#include <hip/hip_runtime.h>
#include <cstdint>
#include <cstddef>

#define HDIM 2048
#define NCLS 11
#define NBLK 256
#define NTHR 256
#define EPB  (HDIM / NBLK)      // 8 h-elements per block
#define CHUNK 256               // h-columns per lane (weights in VGPR/AGPR)
#define CPAD  260               // padded chunk stride in LDS floats

// d_ws: two generation-tagged h-slot buffers (parity = step & 1).
// Slot b (64 B when sw=16): { h[8] (f32), gen (u32), pad }. memset each launch.
//
// Memory-model note: ALL cross-block traffic uses agent-scope ATOMIC ops
// (relaxed). These are sc0/sc1 accesses that write-through to / read-through
// from the coherence point, so no buffer_inv / buffer_wbl2 (L2 nukes) are
// needed — ordering between h stores and the tag store is provided by the
// vmcnt(0) drain inside __syncthreads(). No ACQUIRE/RELEASE/fence anywhere
// in the steady-state loop (R3-R5 showed those cost ~15 us/step in L2
// invalidation side effects).

__device__ __forceinline__ float waveReduceSum(float v) {
#pragma unroll
    for (int off = 32; off > 0; off >>= 1) v += __shfl_xor(v, off, 64);
    return v;
}

// Weight-stationary persistent LSTM, fence-free gen-tagged h exchange.
// Block b owns h[b*8..b*8+8); wave w = gate w; lane (rl=lane>>3, cc=lane&7)
// owns row w*2048+b*8+rl, columns [cc*256, cc*256+256) held in registers.
__global__ void __launch_bounds__(NTHR, 1) lstm_persistent(
    const float* __restrict__ x0,
    const float* __restrict__ Wih,
    const float* __restrict__ Whh,
    const float* __restrict__ bih,
    const float* __restrict__ bhh,
    const float* __restrict__ Wout,
    const float* __restrict__ bout,
    const int* __restrict__ stepsp,
    float* __restrict__ out,
    float* __restrict__ tag0,
    float* __restrict__ tag1,
    int sw)                      // slot stride in floats (>= 9)
{
    const int tid  = threadIdx.x;
    const int wave = tid >> 6;          // gate (i,f,g,o)
    const int lane = tid & 63;
    const int rl   = lane >> 3;         // row within gate for this block
    const int cc   = lane & 7;          // column chunk
    const int bid  = blockIdx.x;
    const int jb   = bid * EPB;

    __shared__ float hlds[8 * CPAD];
    __shared__ float gsm[4 * EPB];
    __shared__ float csm[EPB];

    const int row = wave * HDIM + jb + rl;
    const size_t sbase = (size_t)row * HDIM + (size_t)cc * CHUNK;

    // prefill: w = W_ih slice (step 0 uses W_ih alone since h0 = 0)
    float w[CHUNK];
#pragma unroll
    for (int jj = 0; jj < 64; ++jj) {
        float4 v = *(const float4*)(Wih + sbase + (size_t)jj * 4);
        w[4 * jj + 0] = v.x; w[4 * jj + 1] = v.y;
        w[4 * jj + 2] = v.z; w[4 * jj + 3] = v.w;
    }
    const float bsum = bih[row] + bhh[row];
    if (tid < EPB) csm[tid] = 0.0f;

    const int steps = stepsp[0];
    const int e0   = tid * 8;                              // h elems this thread stages
    const int soff = (tid >> 5) * CPAD + (tid & 31) * 8;   // LDS address of e0

    for (int t = 0; t < steps; ++t) {
        if (t == 0) {
#pragma unroll
            for (int i = 0; i < 8; ++i) hlds[soff + i] = x0[e0 + i];
        } else {
            float* tb   = (t & 1) ? tag1 : tag0;
            float* slot = tb + (size_t)tid * sw;            // thread tid <-> producer block tid
            unsigned* genp = (unsigned*)(slot + 8);
            while (__hip_atomic_load(genp, __ATOMIC_RELAXED, __HIP_MEMORY_SCOPE_AGENT)
                   < (unsigned)t)
                __builtin_amdgcn_s_sleep(1);
            asm volatile("" ::: "memory");   // compiler barrier: no load hoisting
#pragma unroll
            for (int i = 0; i < 8; ++i)
                hlds[soff + i] = __hip_atomic_load(slot + i, __ATOMIC_RELAXED,
                                                   __HIP_MEMORY_SCOPE_AGENT);
        }
        __syncthreads();

        // dot: 256 register weights x LDS-broadcast h chunk
        const float* hc = &hlds[cc * CPAD];
        float ax = 0.f, ay = 0.f, az = 0.f, aw = 0.f;
#pragma unroll
        for (int jj = 0; jj < 64; ++jj) {
            float4 hv = *(const float4*)(hc + jj * 4);
            ax += w[4 * jj + 0] * hv.x;
            ay += w[4 * jj + 1] * hv.y;
            az += w[4 * jj + 2] * hv.z;
            aw += w[4 * jj + 3] * hv.w;
        }
        float part = (ax + ay) + (az + aw);
        part += __shfl_xor(part, 1, 64);
        part += __shfl_xor(part, 2, 64);
        part += __shfl_xor(part, 4, 64);        // summed over cc
        if (cc == 0) gsm[wave * EPB + rl] = part + bsum;
        __syncthreads();

        float* wbuf = ((t + 1) & 1) ? tag1 : tag0;
        float* wslot = wbuf + (size_t)bid * sw;
        if (tid < EPB) {
            float gi = gsm[0 * EPB + tid];
            float gf = gsm[1 * EPB + tid];
            float gg = gsm[2 * EPB + tid];
            float go = gsm[3 * EPB + tid];
            float si = 1.0f / (1.0f + expf(-gi));
            float sf = 1.0f / (1.0f + expf(-gf));
            float tg = tanhf(gg);
            float so = 1.0f / (1.0f + expf(-go));
            float c  = sf * csm[tid] + si * tg;
            csm[tid] = c;
            __hip_atomic_store(wslot + tid, so * tanhf(c),
                               __ATOMIC_RELAXED, __HIP_MEMORY_SCOPE_AGENT);
        }
        __syncthreads();   // vmcnt(0) drain: h stores at coherence point before tag
        if (tid == 0)
            __hip_atomic_store((unsigned*)(wslot + 8), (unsigned)(t + 1),
                               __ATOMIC_RELAXED, __HIP_MEMORY_SCOPE_AGENT);

        if (t == 0) {
            // switch weights to Wc = W_ih + W_hh for steps >= 1
#pragma unroll
            for (int jj = 0; jj < 64; ++jj) {
                float4 v = *(const float4*)(Whh + sbase + (size_t)jj * 4);
                w[4 * jj + 0] += v.x; w[4 * jj + 1] += v.y;
                w[4 * jj + 2] += v.z; w[4 * jj + 3] += v.w;
            }
        }
    }

    // final c
    if (tid < EPB) out[NCLS + HDIM + jb + tid] = csm[tid];

    // block 0: gather final h (gen == steps), classifier head + h copy
    if (bid == 0) {
        float* tb   = (steps & 1) ? tag1 : tag0;
        float* slot = tb + (size_t)tid * sw;
        unsigned* genp = (unsigned*)(slot + 8);
        while (__hip_atomic_load(genp, __ATOMIC_RELAXED, __HIP_MEMORY_SCOPE_AGENT)
               < (unsigned)steps)
            __builtin_amdgcn_s_sleep(1);
        asm volatile("" ::: "memory");
#pragma unroll
        for (int i = 0; i < 8; ++i)
            hlds[soff + i] = __hip_atomic_load(slot + i, __ATOMIC_RELAXED,
                                               __HIP_MEMORY_SCOPE_AGENT);
        __syncthreads();

        __shared__ float lsm[NCLS];
        float hr[8][4];
#pragma unroll
        for (int k = 0; k < 8; ++k)
#pragma unroll
            for (int c = 0; c < 4; ++c)
                hr[k][c] = hlds[k * CPAD + lane * 4 + c];
        for (int r = wave; r < NCLS; r += 4) {
            const float4* w4 = (const float4*)(Wout + (size_t)r * HDIM);
            float sx = 0.f, sy = 0.f, sz = 0.f, sw4 = 0.f;
#pragma unroll
            for (int k = 0; k < 8; ++k) {
                float4 wv = w4[k * 64 + lane];
                sx  += wv.x * hr[k][0];
                sy  += wv.y * hr[k][1];
                sz  += wv.z * hr[k][2];
                sw4 += wv.w * hr[k][3];
            }
            float s = waveReduceSum((sx + sy) + (sz + sw4));
            if (lane == 0) lsm[r] = s + bout[r];
        }
        __syncthreads();
        if (tid == 0) {
            float m = lsm[0];
            for (int r = 1; r < NCLS; ++r) m = fmaxf(m, lsm[r]);
            float ex[NCLS];
            float den = 0.0f;
            for (int r = 0; r < NCLS; ++r) { ex[r] = expf(lsm[r] - m); den += ex[r]; }
            float inv = 1.0f / den;
            for (int r = 0; r < NCLS; ++r) out[r] = ex[r] * inv;
        }
#pragma unroll
        for (int i = 0; i < 8; ++i)
            out[NCLS + e0 + i] = hlds[soff + i];
    }
}

extern "C" void kernel_launch(void* const* d_in, const int* in_sizes, int n_in,
                              void* d_out, int out_size, void* d_ws, size_t ws_size,
                              hipStream_t stream) {
    const float* x0    = (const float*)d_in[0];   // row 0 of inputs
    const float* Wih   = (const float*)d_in[1];
    const float* Whh   = (const float*)d_in[2];
    const float* bih   = (const float*)d_in[3];
    const float* bhh   = (const float*)d_in[4];
    const float* Wout  = (const float*)d_in[5];
    const float* bout  = (const float*)d_in[6];
    const int*   steps = (const int*)d_in[7];
    float* out = (float*)d_out;

    // slot stride: 16 floats (64 B, line-aligned) if workspace allows, else 9
    int sw = 16;
    size_t need = (size_t)2 * NBLK * sw * sizeof(float);   // 32 KiB
    if (ws_size < need) { sw = 9; need = (size_t)2 * NBLK * sw * sizeof(float); }

    float* tag0 = (float*)d_ws;
    float* tag1 = tag0 + (size_t)NBLK * sw;

    // reset generation tags each launch (graph-capture safe, deterministic)
    hipMemsetAsync(d_ws, 0, need, stream);

    lstm_persistent<<<dim3(NBLK), dim3(NTHR), 0, stream>>>(
        x0, Wih, Whh, bih, bhh, Wout, bout, steps, out, tag0, tag1, sw);
}